// Round 8
// baseline (86.634 us; speedup 1.0000x reference)
//
#include <hip/hip_runtime.h>
#include <hip/hip_bf16.h>

typedef __bf16 bf16x8 __attribute__((ext_vector_type(8)));
typedef float  f32x4  __attribute__((ext_vector_type(4)));
typedef float  f32x8  __attribute__((ext_vector_type(8)));
typedef unsigned short us4 __attribute__((ext_vector_type(4)));

#define MFMA16(a, b, c) __builtin_amdgcn_mfma_f32_16x16x32_bf16((a), (b), (c), 0, 0, 0)

constexpr int JJ     = 24;
constexpr int CC     = 64;
constexpr int ROW    = JJ * CC;    // 1536
constexpr int WAVES  = 8;          // 512 threads/block
constexpr int BPW    = 2;
constexpr int BLOCKS = 16384 / (WAVES * BPW);   // 1024
constexpr int WP     = 40;         // pitch (bf16) for weights & PT: 80B rows, ~2-way banks (free)
constexpr float SCALE = 1.0f / 3.0f;  // mean divisor folded into weights & biases

__global__ __launch_bounds__(512, 2) void n2e_kernel(
    const float* __restrict__ node, const float* __restrict__ edge,
    const float* __restrict__ adj,
    const float* __restrict__ Wp, const float* __restrict__ bp,
    const float* __restrict__ Wr, const float* __restrict__ br,
    const float* __restrict__ Wc, const float* __restrict__ bc,
    float* __restrict__ out)
{
    // LDS: weights 3*10240 + PT 8*5120 = 71680 B -> 2 blocks/CU
    __shared__ __bf16 sWc[2 * 64 * WP];     // [ks][d][32(+8 pad)] = (W^T * 1/3) k-blocked
    __shared__ __bf16 sWr[2 * 64 * WP];
    __shared__ __bf16 sWp[2 * 64 * WP];
    __shared__ __bf16 sPT[WAVES][64 * WP];  // per-wave P^T[d][k]

    const int tid = threadIdx.x;
    for (int idx = tid; idx < 4096; idx += 512) {
        int c = idx >> 6, d = idx & 63;
        int dst = (c >> 5) * (64 * WP) + d * WP + (c & 31);
        sWc[dst] = (__bf16)(Wc[idx] * SCALE);
        sWr[dst] = (__bf16)(Wr[idx] * SCALE);
        sWp[dst] = (__bf16)(Wp[idx] * SCALE);
    }
    __syncthreads();   // the ONLY block-wide barrier

    const int lane = tid & 63;
    const int wave = tid >> 6;
    const int r    = lane & 15;
    const int g    = lane >> 4;

    __bf16* myPT = &sPT[wave][0];

    // scaled biases, folded into MFMA C-init
    float bs[4], bpv[4];
    #pragma unroll
    for (int nt = 0; nt < 4; ++nt) {
        int i   = nt * 16 + r;
        bs[nt]  = (bc[i] + br[i]) * SCALE;
        bpv[nt] = bp[i] * SCALE;
    }

    const int  row1s  = (16 + r < JJ) ? (16 + r) : r;  // dup row for j>=24 tail
    const bool adjval = (g < 3);                       // k = g*8+e < 24 only for g<3

    for (int it = 0; it < BPW; ++it) {
        const int b = blockIdx.x * (WAVES * BPW) + wave * BPW + it;
        const float* nf = node + (size_t)b * ROW;
        const float* ef = edge + (size_t)b * ROW;
        const float* af = adj  + (size_t)b * (JJ * JJ);

        // ---- node/edge A-frags (dup rows for tail; masked downstream) ----
        bf16x8 aN[2][2], aE[2][2];
        #pragma unroll
        for (int mt = 0; mt < 2; ++mt) {
            const int row = (mt == 0) ? r : row1s;
            #pragma unroll
            for (int ks = 0; ks < 2; ++ks) {
                f32x8 x = *(const f32x8*)(nf + row * CC + ks * 32 + g * 8);
                f32x8 y = *(const f32x8*)(ef + row * CC + ks * 32 + g * 8);
                bf16x8 an, ae;
                #pragma unroll
                for (int e = 0; e < 8; ++e) { an[e] = (__bf16)x[e]; ae[e] = (__bf16)y[e]; }
                aN[mt][ks] = an; aE[mt][ks] = ae;
            }
        }

        // ---- adj^T A-frags (global gather; zero multiplier in every pad slot) ----
        bf16x8 aA[2];
        #pragma unroll
        for (int mt = 0; mt < 2; ++mt) {
            const int j = mt * 16 + r;
            const bool v = adjval && (j < JJ);
            const float m = v ? 1.0f : 0.0f;
            bf16x8 t;
            #pragma unroll
            for (int e = 0; e < 8; ++e)
                t[e] = (__bf16)(af[v ? ((g * 8 + e) * JJ + j) : 0] * m);
            aA[mt] = t;
        }

        // ---- parent projection FIRST (longest chain: P -> PT -> aggregation) ----
        f32x4 accP[2][4];
        #pragma unroll
        for (int mt = 0; mt < 2; ++mt)
            #pragma unroll
            for (int nt = 0; nt < 4; ++nt)
                accP[mt][nt] = f32x4{bpv[nt], bpv[nt], bpv[nt], bpv[nt]};
        #pragma unroll
        for (int ks = 0; ks < 2; ++ks) {
            #pragma unroll
            for (int nt = 0; nt < 4; ++nt) {
                bf16x8 bW = *(const bf16x8*)(sWp + ks * (64 * WP) + (nt * 16 + r) * WP + g * 8);
                #pragma unroll
                for (int mt = 0; mt < 2; ++mt)
                    accP[mt][nt] = MFMA16(aN[mt][ks], bW, accP[mt][nt]);
            }
        }

        // ---- P -> wave-private PT[d][k] (pitch 40); pad rows finite garbage, killed by aA zeros ----
        #pragma unroll
        for (int mt = 0; mt < 2; ++mt) {
            #pragma unroll
            for (int nt = 0; nt < 4; ++nt) {
                us4 w;
                #pragma unroll
                for (int rr = 0; rr < 4; ++rr)
                    w[rr] = __builtin_bit_cast(unsigned short, (__bf16)accP[mt][nt][rr]);
                *(us4*)(myPT + (nt * 16 + r) * WP + mt * 16 + g * 4) = w;
            }
        }

        // ---- children + recurrent while the PT round-trip drains ----
        f32x4 accCR[2][4];
        #pragma unroll
        for (int mt = 0; mt < 2; ++mt)
            #pragma unroll
            for (int nt = 0; nt < 4; ++nt)
                accCR[mt][nt] = f32x4{bs[nt], bs[nt], bs[nt], bs[nt]};
        #pragma unroll
        for (int ks = 0; ks < 2; ++ks) {
            #pragma unroll
            for (int nt = 0; nt < 4; ++nt) {
                bf16x8 bC = *(const bf16x8*)(sWc + ks * (64 * WP) + (nt * 16 + r) * WP + g * 8);
                bf16x8 bR = *(const bf16x8*)(sWr + ks * (64 * WP) + (nt * 16 + r) * WP + g * 8);
                #pragma unroll
                for (int mt = 0; mt < 2; ++mt) {
                    accCR[mt][nt] = MFMA16(aN[mt][ks], bC, accCR[mt][nt]);
                    accCR[mt][nt] = MFMA16(aE[mt][ks], bR, accCR[mt][nt]);
                }
            }
        }

        // ---- aggregation: adjT x PT, accumulated onto accCR (MFMA C-in) ----
        f32x4 accA[2][4];
        #pragma unroll
        for (int nt = 0; nt < 4; ++nt) {
            bf16x8 bP = *(const bf16x8*)(myPT + (nt * 16 + r) * WP + g * 8);
            #pragma unroll
            for (int mt = 0; mt < 2; ++mt)
                accA[mt][nt] = MFMA16(aA[mt], bP, accCR[mt][nt]);
        }

        // ---- epilogue: out = sigmoid(accA)  (1/3 and all biases pre-folded) ----
        #pragma unroll
        for (int mt = 0; mt < 2; ++mt) {
            #pragma unroll
            for (int rr = 0; rr < 4; ++rr) {
                const int j = mt * 16 + g * 4 + rr;
                if (j < JJ) {
                    float* op = out + (size_t)b * ROW + j * CC + r;
                    #pragma unroll
                    for (int nt = 0; nt < 4; ++nt) {
                        float x = accA[mt][nt][rr];
                        float s = __builtin_amdgcn_rcpf(1.0f + __expf(-x));
                        op[nt * 16] = s;
                    }
                }
            }
        }
    }
}

extern "C" void kernel_launch(void* const* d_in, const int* in_sizes, int n_in,
                              void* d_out, int out_size, void* d_ws, size_t ws_size,
                              hipStream_t stream) {
    const float* node = (const float*)d_in[0];
    const float* edge = (const float*)d_in[1];
    const float* adj  = (const float*)d_in[2];
    const float* Wp   = (const float*)d_in[3];
    const float* bpar = (const float*)d_in[4];
    const float* Wr   = (const float*)d_in[5];
    const float* brec = (const float*)d_in[6];
    const float* Wc   = (const float*)d_in[7];
    const float* bch  = (const float*)d_in[8];

    n2e_kernel<<<BLOCKS, 512, 0, stream>>>(node, edge, adj, Wp, bpar, Wr, brec, Wc, bch,
                                           (float*)d_out);
}